// Round 5
// baseline (320.903 us; speedup 1.0000x reference)
//
#include <hip/hip_runtime.h>

// out[M,N] = x[M,K] @ W_eff[N,K]^T + bias[N],  W_eff = W + 2.0*(B@A)
// M=8192, N=4096, K=4096, R=16.
// Round 5: 8-phase schedule with full-tile prefetch distance: tile kt+2's
// A staged at kt.P3, B at kt.P4 (WAR-safe: A[cur] consumed by P2, B[cur] by
// P3); ONE vmcnt(8) per K-tile at end-P4 draining only loads issued a full
// tile earlier. lgkmcnt(0) without sched_barrier; counted lgkmcnt(8) after
// P1's 12-read burst. T1 XCD swizzle, T2 XOR swizzle, T5 setprio.

typedef __attribute__((ext_vector_type(4))) float f32x4;
typedef __attribute__((ext_vector_type(8))) short bf16x8;

__device__ __forceinline__ unsigned short f2bf(float f) {
    unsigned u = __builtin_bit_cast(unsigned, f);
    unsigned r = u + 0x7fffu + ((u >> 16) & 1u);
    return (unsigned short)(r >> 16);
}

__device__ __forceinline__ void gload_lds16(const void* g, void* l) {
    __builtin_amdgcn_global_load_lds(
        (const __attribute__((address_space(1))) void*)g,
        (__attribute__((address_space(3))) void*)l, 16, 0, 0);
}

// ---------------- cast x (f32 -> bf16) ----------------
__global__ __launch_bounds__(256) void cast_x_kernel(
    const float* __restrict__ x, unsigned short* __restrict__ xb, int n8)
{
    int stride = gridDim.x * blockDim.x;
    for (int i = blockIdx.x * blockDim.x + threadIdx.x; i < n8; i += stride) {
        size_t base = (size_t)i * 8;
        float4 f0 = *(const float4*)&x[base];
        float4 f1 = *(const float4*)&x[base + 4];
        ushort4 o0, o1;
        o0.x = f2bf(f0.x); o0.y = f2bf(f0.y); o0.z = f2bf(f0.z); o0.w = f2bf(f0.w);
        o1.x = f2bf(f1.x); o1.y = f2bf(f1.y); o1.z = f2bf(f1.z); o1.w = f2bf(f1.w);
        *(ushort4*)&xb[base]     = o0;
        *(ushort4*)&xb[base + 4] = o1;
    }
}

// ------------- W_eff = W + scale*(B@A), cast to bf16 -------------
__global__ __launch_bounds__(256) void prep_w_kernel(
    const float* __restrict__ W, const float* __restrict__ A,
    const float* __restrict__ Bl, unsigned short* __restrict__ wb,
    int K, float scale)
{
    __shared__ float Bs[16][16];
    const int t = threadIdx.x;
    const int n0 = blockIdx.y * 16;
    const int k0 = blockIdx.x * 256;
    {
        int nl = t >> 4, r = t & 15;
        Bs[nl][r] = Bl[(size_t)(n0 + nl) * 16 + r];
    }
    __syncthreads();

    const int lane = t & 63;
    const int wv = t >> 6;
    const int k = k0 + lane * 4;

    float4 av[16];
#pragma unroll
    for (int r = 0; r < 16; ++r)
        av[r] = *(const float4*)&A[(size_t)r * K + k];

#pragma unroll
    for (int j = 0; j < 4; ++j) {
        const int nl = wv * 4 + j;
        const int n = n0 + nl;
        float4 w = *(const float4*)&W[(size_t)n * K + k];
        float d0 = 0.f, d1 = 0.f, d2 = 0.f, d3 = 0.f;
#pragma unroll
        for (int r = 0; r < 16; ++r) {
            float b = Bs[nl][r];
            d0 += b * av[r].x; d1 += b * av[r].y;
            d2 += b * av[r].z; d3 += b * av[r].w;
        }
        ushort4 o;
        o.x = f2bf(w.x + scale * d0);
        o.y = f2bf(w.y + scale * d1);
        o.z = f2bf(w.z + scale * d2);
        o.w = f2bf(w.w + scale * d3);
        *(ushort4*)&wb[(size_t)n * K + k] = o;
    }
}

// ---------------- 256x256 8-phase bf16 GEMM + bias ----------------
// 512 threads = 8 waves (2 M x 4 N), each wave owns 128x64 output.
// LDS [dbuf][A/B][half][128*64 bf16] = 128 KiB. BK=64.
// Swizzle: byte ^= (row&7)<<4 via pre-swizzled global source + swizzled read.

#define SETPRIO(p) __builtin_amdgcn_s_setprio(p)
#define BARRIER()  __builtin_amdgcn_s_barrier()

__global__ __launch_bounds__(512, 2) void gemm256_kernel(
    const unsigned short* __restrict__ Xb, const unsigned short* __restrict__ Wb,
    const float* __restrict__ bias, float* __restrict__ out,
    int M, int N, int K)
{
    __shared__ __align__(16) unsigned short lds[2][2][2][8192];

    const int NT = K / 64;
    const int ntn = N / 256;
    int bid = blockIdx.x;
    {   // XCD swizzle (grid 512, divisible by 8 -> simple form bijective)
        int per = gridDim.x >> 3;
        bid = (bid & 7) * per + (bid >> 3);
    }
    const int tm = bid / ntn, tn = bid % ntn;

    const int t = threadIdx.x;
    const int lane = t & 63, wave = t >> 6;
    const int wr = wave >> 2;          // 0..1 -> A half, rows wr*128
    const int wc = wave & 3;           // 0..3 -> cols wc*64

    // ---- staging addresses (pre-swizzled global source, linear LDS dest) ----
    const int srow = t >> 3;                                   // 0..63
    const int scol = ((t & 7) * 8) ^ (((t >> 3) & 7) << 3);    // elements
    unsigned gA[2][2], gB[2][2];
#pragma unroll
    for (int h = 0; h < 2; ++h)
#pragma unroll
        for (int i = 0; i < 2; ++i) {
            gA[h][i] = (unsigned)((tm * 256 + h * 128 + i * 64 + srow) * K + scol);
            gB[h][i] = (unsigned)((tn * 256 + h * 128 + i * 64 + srow) * K + scol);
        }

    // one chunk = 64 rows x 64 cols = 1 gload_lds per thread
#define ST_A(buf, h, i, kt)                                                     \
    gload_lds16(Xb + gA[h][i] + (kt) * 64,                                      \
                &lds[buf][0][h][(i) * 4096 + wave * 512]);
#define ST_B(buf, h, i, kt)                                                     \
    gload_lds16(Wb + gB[h][i] + (kt) * 64,                                      \
                &lds[buf][1][h][(i) * 4096 + wave * 512]);

    // ---- fragment read offsets (swizzled) ----
    const int fr = lane & 15;
    const int hi16 = ((lane >> 4) & 3) * 16;       // k-offset bytes within row
    const int bsw = (fr & 7) << 4;
    const int lo0 = hi16 ^ bsw;                    // kk=0
    const int lo1 = (64 + hi16) ^ bsw;             // kk=1

    f32x4 acc[8][4] = {};

    // ---- prologue: tiles 0,1 fully staged (16 loads) ----
#pragma unroll
    for (int h = 0; h < 2; ++h)
#pragma unroll
        for (int i = 0; i < 2; ++i) { ST_A(0, h, i, 0) ST_B(0, h, i, 0) }
#pragma unroll
    for (int h = 0; h < 2; ++h)
#pragma unroll
        for (int i = 0; i < 2; ++i) { ST_A(1, h, i, 1) ST_B(1, h, i, 1) }
    asm volatile("s_waitcnt vmcnt(8)" ::: "memory");   // tile0 landed
    BARRIER();

#define MFMA_Q(m0, n0)                                                          \
    _Pragma("unroll") for (int mi = m0; mi < m0 + 4; ++mi)                      \
    _Pragma("unroll") for (int ni = n0; ni < n0 + 2; ++ni)                      \
    _Pragma("unroll") for (int kk = 0; kk < 2; ++kk)                            \
        acc[mi][ni] = __builtin_amdgcn_mfma_f32_16x16x32_bf16(                  \
            a[mi][kk], b[ni][kk], acc[mi][ni], 0, 0, 0);

    for (int kt = 0; kt < NT; ++kt) {
        const int cur = kt & 1;
        const char* pA = (const char*)&lds[cur][0][wr][0];
        const char* pB = (const char*)&lds[cur][1][wc >> 1][0];
        const int bro = (wc & 1) * 64;   // B row offset within half
        const bool st = (kt + 2 < NT);   // stage tile kt+2 -> buf[cur]

        bf16x8 a[8][2], b[4][2];

        // ---- P1: read a0-3,b0-1 (12 reads); MFMA Q(0,0) ----
#pragma unroll
        for (int mi = 0; mi < 4; ++mi) {
            a[mi][0] = *(const bf16x8*)(pA + (mi * 16 + fr) * 128 + lo0);
            a[mi][1] = *(const bf16x8*)(pA + (mi * 16 + fr) * 128 + lo1);
        }
#pragma unroll
        for (int ni = 0; ni < 2; ++ni) {
            b[ni][0] = *(const bf16x8*)(pB + (bro + ni * 16 + fr) * 128 + lo0);
            b[ni][1] = *(const bf16x8*)(pB + (bro + ni * 16 + fr) * 128 + lo1);
        }
        asm volatile("s_waitcnt lgkmcnt(8)" ::: "memory");  // pre-drain burst
        BARRIER();
        asm volatile("s_waitcnt lgkmcnt(0)" ::: "memory");
        SETPRIO(1);
        MFMA_Q(0, 0)
        SETPRIO(0);
        BARRIER();

        // ---- P2: read a4-7 (8 reads); MFMA Q(4,0) ----
#pragma unroll
        for (int mi = 4; mi < 8; ++mi) {
            a[mi][0] = *(const bf16x8*)(pA + (mi * 16 + fr) * 128 + lo0);
            a[mi][1] = *(const bf16x8*)(pA + (mi * 16 + fr) * 128 + lo1);
        }
        BARRIER();
        asm volatile("s_waitcnt lgkmcnt(0)" ::: "memory");
        SETPRIO(1);
        MFMA_Q(4, 0)
        SETPRIO(0);
        BARRIER();
        // A[cur] (tile kt) fully consumed by all waves from here.

        // ---- P3: read b2-3 (4 reads); stage A of kt+2 (4 loads); Q(0,2) ----
#pragma unroll
        for (int ni = 2; ni < 4; ++ni) {
            b[ni][0] = *(const bf16x8*)(pB + (bro + ni * 16 + fr) * 128 + lo0);
            b[ni][1] = *(const bf16x8*)(pB + (bro + ni * 16 + fr) * 128 + lo1);
        }
        if (st) {
            ST_A(cur, 0, 0, kt + 2) ST_A(cur, 0, 1, kt + 2)
            ST_A(cur, 1, 0, kt + 2) ST_A(cur, 1, 1, kt + 2)
        }
        BARRIER();
        asm volatile("s_waitcnt lgkmcnt(0)" ::: "memory");
        SETPRIO(1);
        MFMA_Q(0, 2)
        SETPRIO(0);
        BARRIER();
        // B[cur] (tile kt) fully consumed by all waves from here.

        // ---- P4: stage B of kt+2 (4 loads); MFMA Q(4,2); counted vmcnt ----
        if (st) {
            ST_B(cur, 0, 0, kt + 2) ST_B(cur, 0, 1, kt + 2)
            ST_B(cur, 1, 0, kt + 2) ST_B(cur, 1, 1, kt + 2)
        }
        BARRIER();
        SETPRIO(1);
        MFMA_Q(4, 2)
        SETPRIO(0);
        if (st) {   // drain tile kt+1 (issued a full tile ago); kt+2 in flight
            asm volatile("s_waitcnt vmcnt(8)" ::: "memory");
        } else {
            asm volatile("s_waitcnt vmcnt(0)" ::: "memory");
        }
        BARRIER();
    }

    // ---- epilogue: C/D layout col=lane&15, row=(lane>>4)*4+reg ----
    const int row0 = tm * 256 + wr * 128 + (lane >> 4) * 4;
    const int col0 = tn * 256 + wc * 64;
#pragma unroll
    for (int ni = 0; ni < 4; ++ni) {
        const int col = col0 + ni * 16 + fr;
        const float bv = bias[col];
#pragma unroll
        for (int mi = 0; mi < 8; ++mi) {
            const int row = row0 + mi * 16;
#pragma unroll
            for (int r = 0; r < 4; ++r)
                out[(size_t)(row + r) * N + col] = acc[mi][ni][r] + bv;
        }
    }
}

extern "C" void kernel_launch(void* const* d_in, const int* in_sizes, int n_in,
                              void* d_out, int out_size, void* d_ws, size_t ws_size,
                              hipStream_t stream)
{
    const float* x  = (const float*)d_in[0];
    const float* W  = (const float*)d_in[1];
    const float* b  = (const float*)d_in[2];
    const float* A  = (const float*)d_in[3];
    const float* Bl = (const float*)d_in[4];
    float* out = (float*)d_out;

    const int Dout = in_sizes[2];
    const int Din  = in_sizes[1] / Dout;
    const int M    = in_sizes[0] / Din;

    unsigned short* xb = (unsigned short*)d_ws;
    unsigned short* wb = xb + (size_t)M * Din;

    cast_x_kernel<<<2048, 256, 0, stream>>>(x, xb, M * Din / 8);

    dim3 gw(Din / 256, Dout / 16);
    prep_w_kernel<<<gw, 256, 0, stream>>>(W, A, Bl, wb, Din, 2.0f);

    const int grid = (M / 256) * (Dout / 256); // 512
    gemm256_kernel<<<grid, 512, 0, stream>>>(xb, wb, b, out, M, Dout, Din);
}